// Round 8
// baseline (361.074 us; speedup 1.0000x reference)
//
#include <hip/hip_runtime.h>

#define E0     300000
#define E1     75000
#define NSRC0  50000
#define NDST0  20000
#define NDST1  5000
#define EMB    128
#define HID    256
#define NOUT   16

#define NPB        40     // nodes per embed block (1250 * 40 = 50000 exactly)
#define TILE_SHIFT 12     // 4096-row vocab tiles; tiles 0..12

// ---- bf16 helpers (RNE pack, cheap unpack) ----
__device__ __forceinline__ unsigned short f2bf(float f) {
    unsigned u = __float_as_uint(f);
    return (unsigned short)((u + 0x7FFFu + ((u >> 16) & 1u)) >> 16);
}
__device__ __forceinline__ float bflo(unsigned u) { return __uint_as_float(u << 16); }
__device__ __forceinline__ float bfhi(unsigned u) { return __uint_as_float(u & 0xFFFF0000u); }
__device__ __forceinline__ unsigned pack2(float a, float b) {
    return (unsigned)f2bf(a) | ((unsigned)f2bf(b) << 16);
}

// ---------------- prep: f32->bf16 table conv + degree histograms, fused ----------------
// grid covers 800000 threads (tconv); hist piggybacks on the low 300000.
__global__ void prep_kernel(const float* __restrict__ wt, unsigned short* __restrict__ wtb,
                            const int* __restrict__ src0, const int* __restrict__ dst0,
                            const int* __restrict__ src1, const int* __restrict__ dst1,
                            int* cnt0, int* cnt1, int* degO0, int* degO1) {
    int i = blockIdx.x * blockDim.x + threadIdx.x;
    if (i < NSRC0 * EMB / 8) {            // 800000: pack 8 floats -> 8 bf16
        const float4* in = (const float4*)wt;
        float4 v0 = in[i * 2], v1 = in[i * 2 + 1];
        uint4 o;
        o.x = pack2(v0.x, v0.y); o.y = pack2(v0.z, v0.w);
        o.z = pack2(v1.x, v1.y); o.w = pack2(v1.z, v1.w);
        ((uint4*)wtb)[i] = o;
    }
    if (i < E0) {
        atomicAdd(&cnt0[dst0[i]], 1);
        atomicAdd(&degO0[src0[i]], 1);
    }
    if (i < E1) {
        atomicAdd(&cnt1[dst1[i]], 1);
        atomicAdd(&degO1[src1[i]], 1);
    }
}

// ---------------- exclusive scan (2 blocks x 1024 threads) ----------------
__device__ void scan_body(const int* __restrict__ cnt, int n,
                          int* __restrict__ off, int* __restrict__ cur) {
    __shared__ int sums[1024];
    int t = threadIdx.x;
    int chunk = (n + 1023) / 1024;
    int lo = t * chunk, hi = min(lo + chunk, n);
    int s = 0;
    for (int i = lo; i < hi; ++i) s += cnt[i];
    sums[t] = s;
    __syncthreads();
    for (int d = 1; d < 1024; d <<= 1) {
        int x = (t >= d) ? sums[t - d] : 0;
        __syncthreads();
        sums[t] += x;
        __syncthreads();
    }
    int run = (t == 0) ? 0 : sums[t - 1];
    for (int i = lo; i < hi; ++i) {
        off[i] = run; cur[i] = run;
        run += cnt[i];
    }
    if (t == 1023) off[n] = run;
}

__global__ void scan_kernel(const int* cnt0, int* off0, int* cur0,
                            const int* cnt1, int* off1, int* cur1) {
    if (blockIdx.x == 0) scan_body(cnt0, NDST0, off0, cur0);
    else                 scan_body(cnt1, NDST1, off1, cur1);
}

// ---------------- bucket edges by dst (build CSR adjacency) ----------------
__global__ void bucket_kernel(const int* __restrict__ src0, const int* __restrict__ dst0,
                              const int* __restrict__ src1, const int* __restrict__ dst1,
                              int* cur0, int* cur1, int* esrc0, int* esrc1) {
    int i = blockIdx.x * blockDim.x + threadIdx.x;
    if (i < E0) {
        int p = atomicAdd(&cur0[dst0[i]], 1);
        esrc0[p] = src0[i];
    }
    if (i < E1) {
        int p = atomicAdd(&cur1[dst1[i]], 1);
        esrc1[p] = src1[i];
    }
}

// ---------------- fused embedding mean: LDS tile-sort + bf16 gather -------
__global__ void embed_kernel(const int* __restrict__ user_word,
                             const unsigned short* __restrict__ wtb,
                             const int* __restrict__ degO0,
                             unsigned short* __restrict__ x0b) {
    __shared__ int raw[NPB * 50];
    __shared__ int srt[NPB * 50];
    __shared__ int cnt[NPB * 17];        // stride 17: avoids LDS bank conflicts
    int t = threadIdx.x;
    int base = blockIdx.x * NPB * 50;
    for (int j = t; j < NPB * 50; j += 256)
        raw[j] = user_word[base + j];
    for (int j = t; j < NPB * 17; j += 256)
        cnt[j] = 0;
    __syncthreads();
    if (t < NPB) {                                // 1 thread sorts 1 node (in LDS)
        int* c = cnt + t * 17;
        const int* r = raw + t * 50;
        for (int j = 0; j < 50; ++j) c[r[j] >> TILE_SHIFT]++;
        int run = 0;
        for (int b = 0; b < 13; ++b) { int v = c[b]; c[b] = run; run += v; }
        int* o = srt + t * 50;
        for (int j = 0; j < 50; ++j) { int v = r[j]; o[c[v >> TILE_SHIFT]++] = v; }
    }
    __syncthreads();
    int g = t >> 5, l = t & 31;                   // 8 groups of 32 lanes
    const uint2* wt2 = (const uint2*)wtb;         // row = 32 uint2
    for (int n = g; n < NPB; n += 8) {
        const int* id = srt + n * 50;
        float a0 = 0.f, a1 = 0.f, a2 = 0.f, a3 = 0.f;
        #pragma unroll 2
        for (int j = 0; j < 50; j += 2) {
            uint2 v0 = wt2[id[j] * 32 + l];
            uint2 v1 = wt2[id[j + 1] * 32 + l];
            a0 += bflo(v0.x) + bflo(v1.x); a1 += bfhi(v0.x) + bfhi(v1.x);
            a2 += bflo(v0.y) + bflo(v1.y); a3 += bfhi(v0.y) + bfhi(v1.y);
        }
        int node = blockIdx.x * NPB + n;
        float s = rsqrtf(fmaxf((float)degO0[node], 1.0f)) * 0.02f;  // 1/50 mean
        uint2 o2; o2.x = pack2(a0 * s, a1 * s); o2.y = pack2(a2 * s, a3 * s);
        ((uint2*)x0b)[node * 32 + l] = o2;
    }
}

// ---------------- layer1: fused agg1 + gemm1 ----------------
// Block = 256 threads, 16 dst rows. Phase 1: 4 waves aggregate 4 rows each into
// LDS A[16][132] (f32). Phase 2: wave 0 computes C[16x256] = A @ W1 with b128
// A-broadcast reads, 4 cols/lane; epilogue relu * rsqrt(degO1), bf16 store.
__global__ void layer1_kernel(const int* __restrict__ off0, const int* __restrict__ esrc0,
                              const unsigned short* __restrict__ x0b,
                              const int* __restrict__ degO1,
                              const float* __restrict__ W1, const float* __restrict__ b1,
                              unsigned short* __restrict__ h1b) {
    __shared__ float A[16 * 132];     // pad 132 (%4==0: aligned float4 rows)
    __shared__ float s_out[16];
    int t = threadIdx.x;
    int row0 = blockIdx.x * 16;
    int wave = t >> 6, lane = t & 63;
    int half = lane >> 5, l = lane & 31;
    const uint2* x2 = (const uint2*)x0b;
    if (t < 16) s_out[t] = rsqrtf(fmaxf((float)degO1[row0 + t], 1.0f));
    #pragma unroll
    for (int i = 0; i < 4; ++i) {
        int r = wave * 4 + i;
        int d = row0 + r;
        int lo = off0[d], hi = off0[d + 1];
        float a0 = 0.f, a1 = 0.f, a2 = 0.f, a3 = 0.f;
        for (int j = lo + half; j < hi; j += 2) {
            uint2 v = x2[esrc0[j] * 32 + l];
            a0 += bflo(v.x); a1 += bfhi(v.x); a2 += bflo(v.y); a3 += bfhi(v.y);
        }
        a0 += __shfl_down(a0, 32); a1 += __shfl_down(a1, 32);
        a2 += __shfl_down(a2, 32); a3 += __shfl_down(a3, 32);
        if (half == 0) {
            float sc = rsqrtf(fmaxf((float)(hi - lo), 1.0f));
            float4 o; o.x = a0 * sc; o.y = a1 * sc; o.z = a2 * sc; o.w = a3 * sc;
            *(float4*)(A + r * 132 + 4 * l) = o;
        }
    }
    __syncthreads();
    if (t >= 64) return;              // gemm: wave 0 only (no further barriers)
    float acc[16][4];
    #pragma unroll
    for (int r = 0; r < 16; ++r)
        #pragma unroll
        for (int c = 0; c < 4; ++c) acc[r][c] = 0.f;
    for (int k4 = 0; k4 < 32; ++k4) {
        float w[4][4];                // [kk][cc]
        #pragma unroll
        for (int kk = 0; kk < 4; ++kk)
            #pragma unroll
            for (int cc = 0; cc < 4; ++cc)
                w[kk][cc] = W1[(k4 * 4 + kk) * 256 + t + cc * 64];
        #pragma unroll
        for (int r = 0; r < 16; ++r) {
            float4 a = *(const float4*)(A + r * 132 + k4 * 4);   // wave-uniform broadcast
            #pragma unroll
            for (int cc = 0; cc < 4; ++cc)
                acc[r][cc] += a.x * w[0][cc] + a.y * w[1][cc] + a.z * w[2][cc] + a.w * w[3][cc];
        }
    }
    #pragma unroll
    for (int cc = 0; cc < 4; ++cc) {
        int col = t + cc * 64;
        float bb = b1[col];
        #pragma unroll
        for (int r = 0; r < 16; ++r)
            h1b[(row0 + r) * 256 + col] = f2bf(fmaxf(acc[r][cc] + bb, 0.f) * s_out[r]);
    }
}

// ---------------- layer2: fused agg2 + gemm2 (+ labels passthrough) ----------------
// Block = 256 threads, 16 dst1 rows. Phase 1: 4 waves x 4 rows; full 256-wide row
// per 64 lanes (uint2 each). Phase 2: thread (r,c) computes out[row0+r][c].
__global__ void layer2_kernel(const int* __restrict__ off1, const int* __restrict__ esrc1,
                              const unsigned short* __restrict__ h1b,
                              const float* __restrict__ W2, const float* __restrict__ b2,
                              const int* __restrict__ labels,
                              float* __restrict__ out) {
    __shared__ float A[16 * 260];     // pad 260 (%4==0, breaks 16-way bank stride)
    __shared__ float Wl[256 * 16];
    int t = threadIdx.x;
    int row0 = blockIdx.x * 16;
    int wave = t >> 6, l = t & 63;
    const uint2* h2 = (const uint2*)h1b;           // row = 64 uint2
    for (int j = t; j < 256 * 16; j += 256) Wl[j] = W2[j];
    #pragma unroll
    for (int i = 0; i < 4; ++i) {
        int r = wave * 4 + i;
        int d = row0 + r;
        float a0 = 0.f, a1 = 0.f, a2 = 0.f, a3 = 0.f;
        float sc = 0.f;
        if (d < NDST1) {
            int lo = off1[d], hi = off1[d + 1];
            int j = lo;
            for (; j + 1 < hi; j += 2) {
                uint2 v0 = h2[esrc1[j] * 64 + l];
                uint2 v1 = h2[esrc1[j + 1] * 64 + l];
                a0 += bflo(v0.x) + bflo(v1.x); a1 += bfhi(v0.x) + bfhi(v1.x);
                a2 += bflo(v0.y) + bflo(v1.y); a3 += bfhi(v0.y) + bfhi(v1.y);
            }
            if (j < hi) {
                uint2 v = h2[esrc1[j] * 64 + l];
                a0 += bflo(v.x); a1 += bfhi(v.x); a2 += bflo(v.y); a3 += bfhi(v.y);
            }
            sc = rsqrtf(fmaxf((float)(hi - lo), 1.0f));
        }
        float4 o; o.x = a0 * sc; o.y = a1 * sc; o.z = a2 * sc; o.w = a3 * sc;
        *(float4*)(A + r * 260 + 4 * l) = o;
    }
    __syncthreads();
    int r = t >> 4, c = t & 15;
    float acc = 0.0f;
    for (int k = 0; k < 256; ++k)
        acc += A[r * 260 + k] * Wl[k * 16 + c];
    int row = row0 + r;
    if (row < NDST1)
        out[row * NOUT + c] = fmaxf(acc + b2[c], 0.0f);
    if (t < 16 && row0 + t < NDST1)
        out[NDST1 * NOUT + row0 + t] = (float)labels[row0 + t];
}

extern "C" void kernel_launch(void* const* d_in, const int* in_sizes, int n_in,
                              void* d_out, int out_size, void* d_ws, size_t ws_size,
                              hipStream_t stream) {
    const int*   user_word  = (const int*)d_in[0];
    const int*   labels     = (const int*)d_in[1];
    const int*   src0       = (const int*)d_in[2];
    const int*   dst0       = (const int*)d_in[3];
    const int*   src1       = (const int*)d_in[4];
    const int*   dst1       = (const int*)d_in[5];
    const float* word_table = (const float*)d_in[6];
    const float* W1         = (const float*)d_in[7];
    const float* b1         = (const float*)d_in[8];
    const float* W2         = (const float*)d_in[9];
    const float* b2         = (const float*)d_in[10];

    int* iws = (int*)d_ws;
    int* cnt0  = iws;            // 20000  ┐
    int* cnt1  = iws + 20000;    //  5000  │ zeroed (95000 ints)
    int* degO0 = iws + 25000;    // 50000  │
    int* degO1 = iws + 75000;    // 20000  ┘
    int* off0  = iws + 95000;    // 20001
    int* off1  = iws + 115001;   //  5001
    int* cur0  = iws + 120002;   // 20000
    int* cur1  = iws + 140002;   //  5000
    int* esrc0 = iws + 145002;   // 300000
    int* esrc1 = iws + 445002;   // 75000   (end 520002; pad to 520004)
    unsigned short* wtb = (unsigned short*)(iws + 520004);   // 6.4M bf16
    unsigned short* x0b = (unsigned short*)(iws + 3720004);  // 6.4M bf16
    unsigned short* h1b = (unsigned short*)(iws + 6920004);  // 5.12M bf16 (end 9480004 ≈ 38 MB)

    hipMemsetAsync(iws, 0, 95000 * sizeof(int), stream);

    prep_kernel<<<(NSRC0 * EMB / 8 + 255) / 256, 256, 0, stream>>>(
        word_table, wtb, src0, dst0, src1, dst1, cnt0, cnt1, degO0, degO1);
    scan_kernel<<<2, 1024, 0, stream>>>(cnt0, off0, cur0, cnt1, off1, cur1);
    bucket_kernel<<<(E0 + 255) / 256, 256, 0, stream>>>(src0, dst0, src1, dst1,
                                                        cur0, cur1, esrc0, esrc1);
    embed_kernel<<<NSRC0 / NPB, 256, 0, stream>>>(user_word, wtb, degO0, x0b);
    layer1_kernel<<<NDST0 / 16, 256, 0, stream>>>(off0, esrc0, x0b, degO1, W1, b1, h1b);
    layer2_kernel<<<(NDST1 + 15) / 16, 256, 0, stream>>>(off1, esrc1, h1b, W2, b2,
                                                         labels, (float*)d_out);
}

// Round 9
// 324.309 us; speedup vs baseline: 1.1134x; 1.1134x over previous
//
#include <hip/hip_runtime.h>

#define E0     300000
#define E1     75000
#define NSRC0  50000
#define NDST0  20000
#define NDST1  5000
#define EMB    128
#define HID    256
#define NOUT   16

#define NPB        40     // nodes per embed block (1250 * 40 = 50000 exactly)
#define TILE_SHIFT 12     // 4096-row vocab tiles; tiles 0..12

// ---- bf16 helpers (RNE pack, cheap unpack) ----
__device__ __forceinline__ unsigned short f2bf(float f) {
    unsigned u = __float_as_uint(f);
    return (unsigned short)((u + 0x7FFFu + ((u >> 16) & 1u)) >> 16);
}
__device__ __forceinline__ float bflo(unsigned u) { return __uint_as_float(u << 16); }
__device__ __forceinline__ float bfhi(unsigned u) { return __uint_as_float(u & 0xFFFF0000u); }
__device__ __forceinline__ unsigned pack2(float a, float b) {
    return (unsigned)f2bf(a) | ((unsigned)f2bf(b) << 16);
}

// ---------------- prep: f32->bf16 table conv + degree histograms, fused ----------------
__global__ void prep_kernel(const float* __restrict__ wt, unsigned short* __restrict__ wtb,
                            const int* __restrict__ src0, const int* __restrict__ dst0,
                            const int* __restrict__ src1, const int* __restrict__ dst1,
                            int* cnt0, int* cnt1, int* degO0, int* degO1) {
    int i = blockIdx.x * blockDim.x + threadIdx.x;
    if (i < NSRC0 * EMB / 8) {            // 800000: pack 8 floats -> 8 bf16
        const float4* in = (const float4*)wt;
        float4 v0 = in[i * 2], v1 = in[i * 2 + 1];
        uint4 o;
        o.x = pack2(v0.x, v0.y); o.y = pack2(v0.z, v0.w);
        o.z = pack2(v1.x, v1.y); o.w = pack2(v1.z, v1.w);
        ((uint4*)wtb)[i] = o;
    }
    if (i < E0) {
        atomicAdd(&cnt0[dst0[i]], 1);
        atomicAdd(&degO0[src0[i]], 1);
    }
    if (i < E1) {
        atomicAdd(&cnt1[dst1[i]], 1);
        atomicAdd(&degO1[src1[i]], 1);
    }
}

// ---------------- exclusive scan (2 blocks x 1024 threads) ----------------
__device__ void scan_body(const int* __restrict__ cnt, int n,
                          int* __restrict__ off, int* __restrict__ cur) {
    __shared__ int sums[1024];
    int t = threadIdx.x;
    int chunk = (n + 1023) / 1024;
    int lo = t * chunk, hi = min(lo + chunk, n);
    int s = 0;
    for (int i = lo; i < hi; ++i) s += cnt[i];
    sums[t] = s;
    __syncthreads();
    for (int d = 1; d < 1024; d <<= 1) {
        int x = (t >= d) ? sums[t - d] : 0;
        __syncthreads();
        sums[t] += x;
        __syncthreads();
    }
    int run = (t == 0) ? 0 : sums[t - 1];
    for (int i = lo; i < hi; ++i) {
        off[i] = run; cur[i] = run;
        run += cnt[i];
    }
    if (t == 1023) off[n] = run;
}

__global__ void scan_kernel(const int* cnt0, int* off0, int* cur0,
                            const int* cnt1, int* off1, int* cur1) {
    if (blockIdx.x == 0) scan_body(cnt0, NDST0, off0, cur0);
    else                 scan_body(cnt1, NDST1, off1, cur1);
}

// ---------------- bucket edges by dst (build CSR adjacency) ----------------
__global__ void bucket_kernel(const int* __restrict__ src0, const int* __restrict__ dst0,
                              const int* __restrict__ src1, const int* __restrict__ dst1,
                              int* cur0, int* cur1, int* esrc0, int* esrc1) {
    int i = blockIdx.x * blockDim.x + threadIdx.x;
    if (i < E0) {
        int p = atomicAdd(&cur0[dst0[i]], 1);
        esrc0[p] = src0[i];
    }
    if (i < E1) {
        int p = atomicAdd(&cur1[dst1[i]], 1);
        esrc1[p] = src1[i];
    }
}

// ---------------- fused embedding mean: LDS tile-sort + bf16 gather -------
__global__ void embed_kernel(const int* __restrict__ user_word,
                             const unsigned short* __restrict__ wtb,
                             const int* __restrict__ degO0,
                             unsigned short* __restrict__ x0b) {
    __shared__ int raw[NPB * 50];
    __shared__ int srt[NPB * 50];
    __shared__ int cnt[NPB * 17];        // stride 17: avoids LDS bank conflicts
    int t = threadIdx.x;
    int base = blockIdx.x * NPB * 50;
    for (int j = t; j < NPB * 50; j += 256)
        raw[j] = user_word[base + j];
    for (int j = t; j < NPB * 17; j += 256)
        cnt[j] = 0;
    __syncthreads();
    if (t < NPB) {                                // 1 thread sorts 1 node (in LDS)
        int* c = cnt + t * 17;
        const int* r = raw + t * 50;
        for (int j = 0; j < 50; ++j) c[r[j] >> TILE_SHIFT]++;
        int run = 0;
        for (int b = 0; b < 13; ++b) { int v = c[b]; c[b] = run; run += v; }
        int* o = srt + t * 50;
        for (int j = 0; j < 50; ++j) { int v = r[j]; o[c[v >> TILE_SHIFT]++] = v; }
    }
    __syncthreads();
    int g = t >> 5, l = t & 31;                   // 8 groups of 32 lanes
    const uint2* wt2 = (const uint2*)wtb;         // row = 32 uint2
    for (int n = g; n < NPB; n += 8) {
        const int* id = srt + n * 50;
        float a0 = 0.f, a1 = 0.f, a2 = 0.f, a3 = 0.f;
        #pragma unroll 2
        for (int j = 0; j < 50; j += 2) {
            uint2 v0 = wt2[id[j] * 32 + l];
            uint2 v1 = wt2[id[j + 1] * 32 + l];
            a0 += bflo(v0.x) + bflo(v1.x); a1 += bfhi(v0.x) + bfhi(v1.x);
            a2 += bflo(v0.y) + bflo(v1.y); a3 += bfhi(v0.y) + bfhi(v1.y);
        }
        int node = blockIdx.x * NPB + n;
        float s = rsqrtf(fmaxf((float)degO0[node], 1.0f)) * 0.02f;  // 1/50 mean
        uint2 o2; o2.x = pack2(a0 * s, a1 * s); o2.y = pack2(a2 * s, a3 * s);
        ((uint2*)x0b)[node * 32 + l] = o2;
    }
}

// ---------------- layer-1 gather-aggregate (bf16 in/out, 1 wave/dst) ----------
__global__ void agg1_kernel(const int* __restrict__ off0, const int* __restrict__ esrc0,
                            const unsigned short* __restrict__ x0b,
                            unsigned short* __restrict__ agg1b) {
    int d = blockIdx.x;
    int t = threadIdx.x;               // 0..63
    int half = t >> 5, l = t & 31;
    int lo = off0[d], hi = off0[d + 1];
    const uint2* x2 = (const uint2*)x0b;           // row = 32 uint2
    float a0 = 0.f, a1 = 0.f, a2 = 0.f, a3 = 0.f;
    for (int j = lo + half; j < hi; j += 2) {
        uint2 v = x2[esrc0[j] * 32 + l];
        a0 += bflo(v.x); a1 += bfhi(v.x); a2 += bflo(v.y); a3 += bfhi(v.y);
    }
    a0 += __shfl_down(a0, 32); a1 += __shfl_down(a1, 32);
    a2 += __shfl_down(a2, 32); a3 += __shfl_down(a3, 32);
    if (half == 0) {
        float sc = rsqrtf(fmaxf((float)(hi - lo), 1.0f));
        uint2 o; o.x = pack2(a0 * sc, a1 * sc); o.y = pack2(a2 * sc, a3 * sc);
        ((uint2*)agg1b)[d * 32 + l] = o;
    }
}

// ---------------- GEMM1: h1 = relu(agg1 @ W1 + b1) * rsqrt(deg_out1), bf16 out ------
// 256 threads = 256 cols; A tile staged f32 in LDS (pad 132), b128 broadcast reads.
__global__ void gemm1_kernel(const unsigned short* __restrict__ agg1b,
                             const int* __restrict__ degO1,
                             const float* __restrict__ W1, const float* __restrict__ b1,
                             unsigned short* __restrict__ h1b) {
    __shared__ float A[16 * 132];     // pad 132 (%4==0: aligned float4 rows)
    __shared__ float s_out[16];
    int t = threadIdx.x;
    int row0 = blockIdx.x * 16;
    if (t < 16) s_out[t] = rsqrtf(fmaxf((float)degO1[row0 + t], 1.0f));
    const unsigned* ag = (const unsigned*)agg1b + row0 * 64;   // 16 rows x 64 uint
    for (int j = t; j < 16 * 64; j += 256) {
        unsigned v = ag[j];
        int r = j >> 6, p = j & 63;
        A[r * 132 + 2 * p]     = bflo(v);
        A[r * 132 + 2 * p + 1] = bfhi(v);
    }
    __syncthreads();
    float acc[16];
    #pragma unroll
    for (int r = 0; r < 16; ++r) acc[r] = 0.f;
    for (int k4 = 0; k4 < 32; ++k4) {
        float w0 = W1[(k4 * 4 + 0) * 256 + t];     // coalesced across t
        float w1 = W1[(k4 * 4 + 1) * 256 + t];
        float w2 = W1[(k4 * 4 + 2) * 256 + t];
        float w3 = W1[(k4 * 4 + 3) * 256 + t];
        #pragma unroll
        for (int r = 0; r < 16; ++r) {
            float4 a = *(const float4*)(A + r * 132 + k4 * 4);  // b128 broadcast
            acc[r] += a.x * w0 + a.y * w1 + a.z * w2 + a.w * w3;
        }
    }
    float bb = b1[t];
    #pragma unroll
    for (int r = 0; r < 16; ++r)
        h1b[(row0 + r) * 256 + t] = f2bf(fmaxf(acc[r] + bb, 0.f) * s_out[r]);
}

// ---------------- layer-2 gather-aggregate (bf16 in/out, 1 wave/dst) -----------
__global__ void agg2_kernel(const int* __restrict__ off1, const int* __restrict__ esrc1,
                            const unsigned short* __restrict__ h1b,
                            unsigned short* __restrict__ agg2b) {
    int d = blockIdx.x;
    int l = threadIdx.x;               // 0..63
    int lo = off1[d], hi = off1[d + 1];
    const uint2* h2 = (const uint2*)h1b;           // row = 64 uint2
    float a0 = 0.f, a1 = 0.f, a2 = 0.f, a3 = 0.f;
    int j = lo;
    for (; j + 1 < hi; j += 2) {
        uint2 v0 = h2[esrc1[j] * 64 + l];
        uint2 v1 = h2[esrc1[j + 1] * 64 + l];
        a0 += bflo(v0.x) + bflo(v1.x); a1 += bfhi(v0.x) + bfhi(v1.x);
        a2 += bflo(v0.y) + bflo(v1.y); a3 += bfhi(v0.y) + bfhi(v1.y);
    }
    if (j < hi) {
        uint2 v = h2[esrc1[j] * 64 + l];
        a0 += bflo(v.x); a1 += bfhi(v.x); a2 += bflo(v.y); a3 += bfhi(v.y);
    }
    float sc = rsqrtf(fmaxf((float)(hi - lo), 1.0f));
    uint2 o; o.x = pack2(a0 * sc, a1 * sc); o.y = pack2(a2 * sc, a3 * sc);
    ((uint2*)agg2b)[d * 64 + l] = o;
}

// ---------------- GEMM2: out = relu(agg2 @ W2 + b2)  (+ labels passthrough) ----------
__global__ void gemm2_kernel(const unsigned short* __restrict__ agg2b,
                             const float* __restrict__ W2, const float* __restrict__ b2,
                             const int* __restrict__ labels,
                             float* __restrict__ out) {
    __shared__ float A[16 * 260];     // pad 260 (%4==0, breaks 16-way bank stride)
    __shared__ float Wl[256 * 16];
    int t = threadIdx.x;
    int row0 = blockIdx.x * 16;
    for (int j = t; j < 256 * 16; j += 256) Wl[j] = W2[j];
    const unsigned* ag = (const unsigned*)agg2b + row0 * 128;  // 16 rows x 128 uint
    for (int j = t; j < 16 * 128; j += 256) {
        int r = j >> 7, p = j & 127;
        unsigned v = (row0 + r < NDST1) ? ag[j] : 0u;
        A[r * 260 + 2 * p]     = bflo(v);
        A[r * 260 + 2 * p + 1] = bfhi(v);
    }
    __syncthreads();
    int r = t >> 4, c = t & 15;
    float acc = 0.0f;
    for (int k4 = 0; k4 < 64; ++k4) {
        float4 a = *(const float4*)(A + r * 260 + k4 * 4);     // b128, 2-way alias free
        acc += a.x * Wl[(k4 * 4 + 0) * 16 + c] + a.y * Wl[(k4 * 4 + 1) * 16 + c]
             + a.z * Wl[(k4 * 4 + 2) * 16 + c] + a.w * Wl[(k4 * 4 + 3) * 16 + c];
    }
    int row = row0 + r;
    if (row < NDST1)
        out[row * NOUT + c] = fmaxf(acc + b2[c], 0.0f);
    if (t < 16 && row0 + t < NDST1)
        out[NDST1 * NOUT + row0 + t] = (float)labels[row0 + t];
}

extern "C" void kernel_launch(void* const* d_in, const int* in_sizes, int n_in,
                              void* d_out, int out_size, void* d_ws, size_t ws_size,
                              hipStream_t stream) {
    const int*   user_word  = (const int*)d_in[0];
    const int*   labels     = (const int*)d_in[1];
    const int*   src0       = (const int*)d_in[2];
    const int*   dst0       = (const int*)d_in[3];
    const int*   src1       = (const int*)d_in[4];
    const int*   dst1       = (const int*)d_in[5];
    const float* word_table = (const float*)d_in[6];
    const float* W1         = (const float*)d_in[7];
    const float* b1         = (const float*)d_in[8];
    const float* W2         = (const float*)d_in[9];
    const float* b2         = (const float*)d_in[10];

    int* iws = (int*)d_ws;
    int* cnt0  = iws;            // 20000  ┐
    int* cnt1  = iws + 20000;    //  5000  │ zeroed (95000 ints)
    int* degO0 = iws + 25000;    // 50000  │
    int* degO1 = iws + 75000;    // 20000  ┘
    int* off0  = iws + 95000;    // 20001
    int* off1  = iws + 115001;   //  5001
    int* cur0  = iws + 120002;   // 20000
    int* cur1  = iws + 140002;   //  5000
    int* esrc0 = iws + 145002;   // 300000
    int* esrc1 = iws + 445002;   // 75000   (end 520002; pad to 520004)
    unsigned short* wtb   = (unsigned short*)(iws + 520004);    // 6.4M bf16
    unsigned short* x0b   = (unsigned short*)(iws + 3720004);   // 6.4M bf16
    unsigned short* h1b   = (unsigned short*)(iws + 6920004);   // 5.12M bf16
    unsigned short* agg1b = (unsigned short*)(iws + 9480004);   // 2.56M bf16
    unsigned short* agg2b = (unsigned short*)(iws + 10760004);  // 1.28M bf16 (end ≈ 45.6 MB)

    hipMemsetAsync(iws, 0, 95000 * sizeof(int), stream);

    prep_kernel<<<(NSRC0 * EMB / 8 + 255) / 256, 256, 0, stream>>>(
        word_table, wtb, src0, dst0, src1, dst1, cnt0, cnt1, degO0, degO1);
    scan_kernel<<<2, 1024, 0, stream>>>(cnt0, off0, cur0, cnt1, off1, cur1);
    bucket_kernel<<<(E0 + 255) / 256, 256, 0, stream>>>(src0, dst0, src1, dst1,
                                                        cur0, cur1, esrc0, esrc1);
    embed_kernel<<<NSRC0 / NPB, 256, 0, stream>>>(user_word, wtb, degO0, x0b);
    agg1_kernel<<<NDST0, 64, 0, stream>>>(off0, esrc0, x0b, agg1b);
    gemm1_kernel<<<NDST0 / 16, 256, 0, stream>>>(agg1b, degO1, W1, b1, h1b);
    agg2_kernel<<<NDST1, 64, 0, stream>>>(off1, esrc1, h1b, agg2b);
    gemm2_kernel<<<(NDST1 + 15) / 16, 256, 0, stream>>>(agg2b, W2, b2, labels, (float*)d_out);
}